// Round 15
// baseline (124.087 us; speedup 1.0000x reference)
//
#include <hip/hip_runtime.h>

#define PEPS  1e-5f
#define LOG2E 1.4426950408889634f

__device__ __forceinline__ float fast_rcp(float x) { return __builtin_amdgcn_rcpf(x); }

// Pair-shared sigmoid blend: one v_rcp per two elements (trans-pipe relief).
__device__ __forceinline__ void patch_pair(float& x, float& y, float nrs2, float mrs) {
    const float tx = fminf(fmaf(x, nrs2, mrs), 60.0f);
    const float ty = fminf(fmaf(y, nrs2, mrs), 60.0f);
    const float ex = __builtin_amdgcn_exp2f(tx);
    const float ey = __builtin_amdgcn_exp2f(ty);
    const float ax = 1.0f + ex;
    const float ay = 1.0f + ey;
    const float r  = fast_rcp(ax * ay);
    x = x * fmaf(0.5f, r * ay, 0.5f);
    y = y * fmaf(0.5f, r * ax, 0.5f);
}

__device__ __forceinline__ void patch_quad(float4& t, float nrs2, float mrs) {
    patch_pair(t.x, t.y, nrs2, mrs);
    patch_pair(t.z, t.w, nrs2, mrs);
}

__device__ __forceinline__ void wave_reduce2(float& a, float& b) {
#pragma unroll
    for (int off = 32; off; off >>= 1) {
        a += __shfl_xor(a, off);
        b += __shfl_xor(b, off);
    }
}

// async global->LDS, 16 B per lane (LDS dest wave-uniform base, src per-lane).
__device__ __forceinline__ void gld_lds16(const float* g, float* l) {
    __builtin_amdgcn_global_load_lds(
        (const __attribute__((address_space(1))) void*)g,
        (__attribute__((address_space(3))) void*)l, 16, 0, 0);
}

// r14 base (113.0us) with ONE isolated change: EARLY PREFETCH ISSUE.
// r8/r10/r11/r14 (4 barrier/wait variants, all 113-114us) proved wait
// placement is not the residual. Timeline analysis: HBM has NOTHING pending
// during phase C (~3us/image) — B's loads are consumed, stores not yet
// issued, and the prefetch was issued only after D. Fix: release the tile
// with a cheap raw s_barrier right after B (top waves' ds_reads already
// consumed; bottom waves never touch the tile) and issue E there, so the
// prefetch drains under C+F+G+H (~8us window vs 5.2us of HBM work, vs the
// old F..H ~5us marginal window).
// Per-wave vmem FIFO at A(k) unchanged: [8 prefetch] older than [16 stores]
// -> vmcnt(16) still retires exactly the prefetch.
// Failure signatures: spill -> VGPR=64/SGPR=112/WRITE>280MB; absmax blowup ->
// tile race; dur unchanged -> phase schedule is not the residual (roofline
// proximity for this structure).
__global__ __launch_bounds__(1024) void fused_pyramid_pipe7(
    const float* __restrict__ in, float* __restrict__ out)
{
    constexpr int W   = 256;
    constexpr int IMG = W * W;                  // 65536 floats
    __shared__ float tile[32768];               // 128 KiB: rows 0..127 of current image
    __shared__ float redS[16], redQ[16];        // pass-2 partials
    __shared__ float redS2[16], redQ2[16];      // pass-3 partials

    const int tid   = threadIdx.x;
    const int wave  = tid >> 6;                 // 0..15 -> 4x4 grid of 64x64 patches
    const int lane  = tid & 63;
    const int pr    = wave >> 2;
    const int pc    = wave & 3;
    const int rlane = lane >> 4;                // row contribution from lane
    const int c4    = lane & 15;
    const int bid   = blockIdx.x;

    // ---- prologue: prefetch image bid's top half into LDS ------------------
    {
        const float* src = in + (size_t)bid * IMG;
#pragma unroll
        for (int i = 0; i < 8; ++i) {
            const int chunk = wave * 8 + i;     // 128 chunks x 1024 B cover 128 KiB
            gld_lds16(src + chunk * 256 + lane * 4, &tile[chunk * 256]);
        }
    }

    for (int k = 0; k < 4; ++k) {
        const int img = bid + k * 256;
        const float* in_img  = in  + (size_t)img * IMG;
        float*       out_img = out + (size_t)img * IMG;

        // A: wait own prefetch (counted — H-stores keep draining under B),
        //    then raw barrier.
        if (k == 0) { asm volatile("s_waitcnt vmcnt(0)" ::: "memory"); }
        else        { asm volatile("s_waitcnt vmcnt(16)" ::: "memory"); }
        __builtin_amdgcn_s_barrier();
        __builtin_amdgcn_sched_barrier(0);

        // B: load v[16] + pass-1 sums. Top waves from LDS, bottom from global.
        float4 v[16];
        float s = 0.f, q = 0.f;
        if (wave < 8) {
            const float* tl = &tile[(pr * 64) * W + pc * 64];
#pragma unroll
            for (int u = 0; u < 16; ++u) {
                const int r = u * 4 + rlane;
                const float4 t = *reinterpret_cast<const float4*>(tl + r * W + c4 * 4);
                v[u] = t;
                s += (t.x + t.y) + (t.z + t.w);
                q = fmaf(t.x, t.x, fmaf(t.y, t.y, fmaf(t.z, t.z, fmaf(t.w, t.w, q))));
            }
        } else {
            const float* gl = in_img + (size_t)(pr * 64) * W + pc * 64;
#pragma unroll
            for (int u = 0; u < 16; ++u) {
                const int r = u * 4 + rlane;
                const float4 t = *reinterpret_cast<const float4*>(gl + (size_t)r * W + c4 * 4);
                v[u] = t;
                s += (t.x + t.y) + (t.z + t.w);
                q = fmaf(t.x, t.x, fmaf(t.y, t.y, fmaf(t.z, t.z, fmaf(t.w, t.w, q))));
            }
        }

        // B': tile-release barrier (all loads consumed) + EARLY prefetch issue
        //     — the prefetch now drains under C+F+G+H instead of F..H.
        asm volatile("s_waitcnt lgkmcnt(0)" ::: "memory");
        __builtin_amdgcn_s_barrier();
        if (k < 3) {
            const float* src = in + (size_t)(bid + (k + 1) * 256) * IMG;
#pragma unroll
            for (int i = 0; i < 8; ++i) {
                const int chunk = wave * 8 + i;
                gld_lds16(src + chunk * 256 + lane * 4, &tile[chunk * 256]);
            }
        }
        __builtin_amdgcn_sched_barrier(0);

        // C: pass 1 (s=64), wave-local
        wave_reduce2(s, q);
        float m  = s * (1.0f / 4096.0f);
        float rs = rsqrtf(fmaf(-m, m, q * (1.0f / 4096.0f)) + PEPS);
        float nrs2 = rs * -LOG2E;
        float mrs  = m * rs * LOG2E;

        float s2 = 0.f, q2 = 0.f;
#pragma unroll
        for (int u = 0; u < 16; ++u) {
            float4 t = v[u];
            patch_quad(t, nrs2, mrs);
            v[u] = t;
            s2 += (t.x + t.y) + (t.z + t.w);
            q2 = fmaf(t.x, t.x, fmaf(t.y, t.y, fmaf(t.z, t.z, fmaf(t.w, t.w, q2))));
        }

        // D: publish pass-2 partials; raw barrier (LDS ordering only)
        wave_reduce2(s2, q2);
        if (lane == 0) { redS[wave] = s2; redQ[wave] = q2; }
        asm volatile("s_waitcnt lgkmcnt(0)" ::: "memory");
        __builtin_amdgcn_s_barrier();

        // F: pass 2 (s=128): 2x2 wave group
        const int w00 = wave & ~5;
        {
            const float S = (redS[w00] + redS[w00 + 1]) + (redS[w00 + 4] + redS[w00 + 5]);
            const float Q = (redQ[w00] + redQ[w00 + 1]) + (redQ[w00 + 4] + redQ[w00 + 5]);
            m  = S * (1.0f / 16384.0f);
            rs = rsqrtf(fmaf(-m, m, Q * (1.0f / 16384.0f)) + PEPS);
        }
        nrs2 = rs * -LOG2E;
        mrs  = m * rs * LOG2E;

        float s3 = 0.f, q3 = 0.f;
#pragma unroll
        for (int u = 0; u < 16; ++u) {
            float4 t = v[u];
            patch_quad(t, nrs2, mrs);
            v[u] = t;
            s3 += (t.x + t.y) + (t.z + t.w);
            q3 = fmaf(t.x, t.x, fmaf(t.y, t.y, fmaf(t.z, t.z, fmaf(t.w, t.w, q3))));
        }

        // G: pass 3 (s=256): publish partials; raw barrier (no vmcnt drain)
        wave_reduce2(s3, q3);
        if (lane == 0) { redS2[wave] = s3; redQ2[wave] = q3; }
        asm volatile("s_waitcnt lgkmcnt(0)" ::: "memory");
        __builtin_amdgcn_s_barrier();
        __builtin_amdgcn_sched_barrier(0);
        {
            float S = 0.f, Q = 0.f;
#pragma unroll
            for (int w = 0; w < 16; ++w) { S += redS2[w]; Q += redQ2[w]; }
            m  = S * (1.0f / 65536.0f);
            rs = rsqrtf(fmaf(-m, m, Q * (1.0f / 65536.0f)) + PEPS);
        }
        nrs2 = rs * -LOG2E;
        mrs  = m * rs * LOG2E;

        // H: apply pass 3 + store
        {
            float* go = out_img + (size_t)(pr * 64) * W + pc * 64;
#pragma unroll
            for (int u = 0; u < 16; ++u) {
                const int r = u * 4 + rlane;
                float4 t = v[u];
                patch_quad(t, nrs2, mrs);
                *reinterpret_cast<float4*>(go + (size_t)r * W + c4 * 4) = t;
            }
        }
    }
}

extern "C" void kernel_launch(void* const* d_in, const int* in_sizes, int n_in,
                              void* d_out, int out_size, void* d_ws, size_t ws_size,
                              hipStream_t stream)
{
    const float* x = (const float*)d_in[0];
    float* out = (float*)d_out;
    // 1024 images, 256 persistent blocks x 4 images each; no workspace needed.
    fused_pyramid_pipe7<<<256, 1024, 0, stream>>>(x, out);
}

// Round 16
// 113.472 us; speedup vs baseline: 1.0935x; 1.0935x over previous
//
#include <hip/hip_runtime.h>

#define PEPS  1e-5f
#define LOG2E 1.4426950408889634f

__device__ __forceinline__ float fast_rcp(float x) { return __builtin_amdgcn_rcpf(x); }

// Pair-shared sigmoid blend: one v_rcp per two elements (trans-pipe relief).
__device__ __forceinline__ void patch_pair(float& x, float& y, float nrs2, float mrs) {
    const float tx = fminf(fmaf(x, nrs2, mrs), 60.0f);
    const float ty = fminf(fmaf(y, nrs2, mrs), 60.0f);
    const float ex = __builtin_amdgcn_exp2f(tx);
    const float ey = __builtin_amdgcn_exp2f(ty);
    const float ax = 1.0f + ex;
    const float ay = 1.0f + ey;
    const float r  = fast_rcp(ax * ay);
    x = x * fmaf(0.5f, r * ay, 0.5f);
    y = y * fmaf(0.5f, r * ax, 0.5f);
}

__device__ __forceinline__ void patch_quad(float4& t, float nrs2, float mrs) {
    patch_pair(t.x, t.y, nrs2, mrs);
    patch_pair(t.z, t.w, nrs2, mrs);
}

__device__ __forceinline__ void wave_reduce2(float& a, float& b) {
#pragma unroll
    for (int off = 32; off; off >>= 1) {
        a += __shfl_xor(a, off);
        b += __shfl_xor(b, off);
    }
}

// async global->LDS, 16 B per lane (LDS dest wave-uniform base, src per-lane).
__device__ __forceinline__ void gld_lds16(const float* g, float* l) {
    __builtin_amdgcn_global_load_lds(
        (const __attribute__((address_space(1))) void*)g,
        (__attribute__((address_space(3))) void*)l, 16, 0, 0);
}

// r14 champion (113.0us) + ONE edit: amdgpu_waves_per_eu(4,4).
// Hidden-spill hypothesis: every 1024-thr variant whose counters we saw
// (r9/r12) had VGPR=64/SGPR=112 — the allocator targets 8 waves/EU (64-VGPR
// budget) even though 1024 thr + 128 KiB LDS geometrically caps the CU at
// ONE block = 4 waves/EU. If the champion shares that target, v[16] (64 data
// regs + ~25 temps) partially spills, and the 7us/image residual over the
// 21.3us HBM floor is scratch traffic — explaining why 5 barrier-schedule
// variants (r8/r10/r11/r14/r15) all plateaued at 113us. Pinning min=max=4
// waves/EU grants the 128-VGPR budget that the geometry already forces;
// ~90-reg peak then fits with margin. (r5's failed (4,4) was on 512-thr
// blocks where 8 waves/EU was a real occupancy option; here it is not.)
// Prediction: spill-fix -> ~96-104us; unchanged -> champion was clean and
// 113us is this schedule's structural limit.
__global__ __attribute__((amdgpu_flat_work_group_size(1024, 1024),
                          amdgpu_waves_per_eu(4, 4)))
void fused_pyramid_pipe8(const float* __restrict__ in, float* __restrict__ out)
{
    constexpr int W   = 256;
    constexpr int IMG = W * W;                  // 65536 floats
    __shared__ float tile[32768];               // 128 KiB: rows 0..127 of current image
    __shared__ float redS[16], redQ[16];        // pass-2 partials
    __shared__ float redS2[16], redQ2[16];      // pass-3 partials

    const int tid   = threadIdx.x;
    const int wave  = tid >> 6;                 // 0..15 -> 4x4 grid of 64x64 patches
    const int lane  = tid & 63;
    const int pr    = wave >> 2;
    const int pc    = wave & 3;
    const int rlane = lane >> 4;                // row contribution from lane
    const int c4    = lane & 15;
    const int bid   = blockIdx.x;

    // ---- prologue: prefetch image bid's top half into LDS ------------------
    {
        const float* src = in + (size_t)bid * IMG;
#pragma unroll
        for (int i = 0; i < 8; ++i) {
            const int chunk = wave * 8 + i;     // 128 chunks x 1024 B cover 128 KiB
            gld_lds16(src + chunk * 256 + lane * 4, &tile[chunk * 256]);
        }
    }

    for (int k = 0; k < 4; ++k) {
        const int img = bid + k * 256;
        const float* in_img  = in  + (size_t)img * IMG;
        float*       out_img = out + (size_t)img * IMG;

        // A: wait own prefetch (counted — H-stores keep draining under B),
        //    then raw barrier.
        if (k == 0) { asm volatile("s_waitcnt vmcnt(0)" ::: "memory"); }
        else        { asm volatile("s_waitcnt vmcnt(16)" ::: "memory"); }
        __builtin_amdgcn_s_barrier();
        __builtin_amdgcn_sched_barrier(0);

        // B: load v[16] + pass-1 sums. Top waves from LDS, bottom from global.
        float4 v[16];
        float s = 0.f, q = 0.f;
        if (wave < 8) {
            const float* tl = &tile[(pr * 64) * W + pc * 64];
#pragma unroll
            for (int u = 0; u < 16; ++u) {
                const int r = u * 4 + rlane;
                const float4 t = *reinterpret_cast<const float4*>(tl + r * W + c4 * 4);
                v[u] = t;
                s += (t.x + t.y) + (t.z + t.w);
                q = fmaf(t.x, t.x, fmaf(t.y, t.y, fmaf(t.z, t.z, fmaf(t.w, t.w, q))));
            }
        } else {
            const float* gl = in_img + (size_t)(pr * 64) * W + pc * 64;
#pragma unroll
            for (int u = 0; u < 16; ++u) {
                const int r = u * 4 + rlane;
                const float4 t = *reinterpret_cast<const float4*>(gl + (size_t)r * W + c4 * 4);
                v[u] = t;
                s += (t.x + t.y) + (t.z + t.w);
                q = fmaf(t.x, t.x, fmaf(t.y, t.y, fmaf(t.z, t.z, fmaf(t.w, t.w, q))));
            }
        }

        // C: pass 1 (s=64), wave-local
        wave_reduce2(s, q);
        float m  = s * (1.0f / 4096.0f);
        float rs = rsqrtf(fmaf(-m, m, q * (1.0f / 4096.0f)) + PEPS);
        float nrs2 = rs * -LOG2E;
        float mrs  = m * rs * LOG2E;

        float s2 = 0.f, q2 = 0.f;
#pragma unroll
        for (int u = 0; u < 16; ++u) {
            float4 t = v[u];
            patch_quad(t, nrs2, mrs);
            v[u] = t;
            s2 += (t.x + t.y) + (t.z + t.w);
            q2 = fmaf(t.x, t.x, fmaf(t.y, t.y, fmaf(t.z, t.z, fmaf(t.w, t.w, q2))));
        }

        // D: publish pass-2 partials; raw barrier (LDS ordering only — the
        //    previous image's stores stay in flight)
        wave_reduce2(s2, q2);
        if (lane == 0) { redS[wave] = s2; redQ[wave] = q2; }
        asm volatile("s_waitcnt lgkmcnt(0)" ::: "memory");
        __builtin_amdgcn_s_barrier();

        // E: kick off next image's top-half prefetch (flies under F/G/H)
        if (k < 3) {
            const float* src = in + (size_t)(bid + (k + 1) * 256) * IMG;
#pragma unroll
            for (int i = 0; i < 8; ++i) {
                const int chunk = wave * 8 + i;
                gld_lds16(src + chunk * 256 + lane * 4, &tile[chunk * 256]);
            }
        }

        // F: pass 2 (s=128): 2x2 wave group
        const int w00 = wave & ~5;
        {
            const float S = (redS[w00] + redS[w00 + 1]) + (redS[w00 + 4] + redS[w00 + 5]);
            const float Q = (redQ[w00] + redQ[w00 + 1]) + (redQ[w00 + 4] + redQ[w00 + 5]);
            m  = S * (1.0f / 16384.0f);
            rs = rsqrtf(fmaf(-m, m, Q * (1.0f / 16384.0f)) + PEPS);
        }
        nrs2 = rs * -LOG2E;
        mrs  = m * rs * LOG2E;

        float s3 = 0.f, q3 = 0.f;
#pragma unroll
        for (int u = 0; u < 16; ++u) {
            float4 t = v[u];
            patch_quad(t, nrs2, mrs);
            v[u] = t;
            s3 += (t.x + t.y) + (t.z + t.w);
            q3 = fmaf(t.x, t.x, fmaf(t.y, t.y, fmaf(t.z, t.z, fmaf(t.w, t.w, q3))));
        }

        // G: pass 3 (s=256): publish partials; raw barrier (no vmcnt drain)
        wave_reduce2(s3, q3);
        if (lane == 0) { redS2[wave] = s3; redQ2[wave] = q3; }
        asm volatile("s_waitcnt lgkmcnt(0)" ::: "memory");
        __builtin_amdgcn_s_barrier();
        __builtin_amdgcn_sched_barrier(0);
        {
            float S = 0.f, Q = 0.f;
#pragma unroll
            for (int w = 0; w < 16; ++w) { S += redS2[w]; Q += redQ2[w]; }
            m  = S * (1.0f / 65536.0f);
            rs = rsqrtf(fmaf(-m, m, Q * (1.0f / 65536.0f)) + PEPS);
        }
        nrs2 = rs * -LOG2E;
        mrs  = m * rs * LOG2E;

        // H: apply pass 3 + store
        {
            float* go = out_img + (size_t)(pr * 64) * W + pc * 64;
#pragma unroll
            for (int u = 0; u < 16; ++u) {
                const int r = u * 4 + rlane;
                float4 t = v[u];
                patch_quad(t, nrs2, mrs);
                *reinterpret_cast<float4*>(go + (size_t)r * W + c4 * 4) = t;
            }
        }
    }
}

extern "C" void kernel_launch(void* const* d_in, const int* in_sizes, int n_in,
                              void* d_out, int out_size, void* d_ws, size_t ws_size,
                              hipStream_t stream)
{
    const float* x = (const float*)d_in[0];
    float* out = (float*)d_out;
    // 1024 images, 256 persistent blocks x 4 images each; no workspace needed.
    fused_pyramid_pipe8<<<256, 1024, 0, stream>>>(x, out);
}